// Round 11
// baseline (228.611 us; speedup 1.0000x reference)
//
#include <hip/hip_runtime.h>
#include <math.h>

namespace {
constexpr int Bn = 8, Cn = 3, Hn = 512, Wn = 960;
constexpr int TPB = 256;
constexpr int CH8 = Wn / 8;                     // 120 8-px chunks per row
constexpr int NBLK1 = Bn * Hn * CH8 / TPB;      // 1920 (pass_warp blocks)
constexpr int NBLK2 = Bn * Hn * CH8 / TPB;      // 1920 (pass_ssim blocks)
constexpr size_t PLANE = (size_t)Bn * Hn * Wn;  // 3,932,160 px
// ws float layout: pad16 | red1 2*NBLK1 | red2 NBLK2 | bf16 planes (3*PLANE ushort) | vw plane (PLANE f32)
constexpr size_t RED1_OFF = 16;
constexpr size_t RED2_OFF = RED1_OFF + 2 * (size_t)NBLK1;   // 3856
constexpr size_t BF_OFF   = RED2_OFF + (size_t)NBLK2;       // 5776 floats (16B aligned)
constexpr size_t VW_OFF   = BF_OFF + (3 * PLANE) / 2;       // floats (16B aligned)
constexpr size_t WS_NEED  = (VW_OFF + PLANE) * sizeof(float);
constexpr float kC1 = 1e-4f;        // 0.01^2
constexpr float kC2 = 9e-4f;        // 0.03^2
constexpr float kEps2 = 1e-6f;      // 0.001^2
constexpr float A3 = 0.85f / 3.f;   // alpha/3
constexpr float B3 = 0.05f;         // (1-alpha)/3
}

__device__ __forceinline__ float gath1(const float* __restrict__ row, float xs) {
    float xf = floorf(xs);
    float wx = xs - xf;
    int xi = (int)xf;
    int a0 = min(max(xi, 0), Wn - 1);
    int a1 = min(max(xi + 1, 0), Wn - 1);
    return (1.f - wx) * row[a0] + wx * row[a1];
}

__device__ __forceinline__ unsigned short f2bf(float f) {   // RTNE
    unsigned u = __float_as_uint(f);
    u += 0x7fffu + ((u >> 16) & 1u);
    return (unsigned short)(u >> 16);
}
__device__ __forceinline__ float bf2f(unsigned short h) {
    return __uint_as_float(((unsigned)h) << 16);
}
__device__ __forceinline__ unsigned packbf(float a, float b) {
    return (unsigned)f2bf(a) | ((unsigned)f2bf(b) << 16);
}

// ---- Pass 1: warp right -> bf16 planes; vw plane (f32); per-block (v,l) slots ----
__global__ __launch_bounds__(TPB) void pass_warp(
    const float* __restrict__ right, const float* __restrict__ d_left,
    const float* __restrict__ d_right, const float* __restrict__ nonocc,
    unsigned short* __restrict__ wbf, float* __restrict__ vwp,
    float* __restrict__ red1)
{
    __shared__ float red[2][TPB / 64];
    const int t = threadIdx.x;
    int flat = blockIdx.x * TPB + t;
    int xq = flat % CH8;
    int rest = flat / CH8;
    int y = rest % Hn;
    int b = rest / Hn;
    int x0 = xq * 8;
    size_t rowoff = ((size_t)b * Hn + y) * Wn;

    float4 d4a = *(const float4*)(d_left + rowoff + x0);
    float4 d4b = *(const float4*)(d_left + rowoff + x0 + 4);
    float4 n4a = *(const float4*)(nonocc + rowoff + x0);
    float4 n4b = *(const float4*)(nonocc + rowoff + x0 + 4);
    float ds[8] = {d4a.x, d4a.y, d4a.z, d4a.w, d4b.x, d4b.y, d4b.z, d4b.w};
    float ns[8] = {n4a.x, n4a.y, n4a.z, n4a.w, n4b.x, n4b.y, n4b.z, n4b.w};
    float xs[8], vw[8];
    float vsum = 0.f, lsum = 0.f;
    const float* drow = d_right + rowoff;
    #pragma unroll
    for (int j = 0; j < 8; ++j) {
        xs[j] = (float)(x0 + j) - ds[j];
        float gx = 2.f * xs[j] / (float)(Wn - 1) - 1.f;
        float vm = (gx >= -1.f && gx <= 1.f) ? 1.f : 0.f;
        vw[j] = vm * ns[j];
        vsum += vw[j];
        float drw = gath1(drow, xs[j]);
        float dd = ds[j] - drw;
        lsum += __builtin_amdgcn_sqrtf(dd * dd + kEps2) * vw[j];
    }
    *(float4*)(vwp + rowoff + x0)     = float4{vw[0], vw[1], vw[2], vw[3]};
    *(float4*)(vwp + rowoff + x0 + 4) = float4{vw[4], vw[5], vw[6], vw[7]};

    #pragma unroll
    for (int c = 0; c < Cn; ++c) {
        const float* rrow = right + ((size_t)(b * Cn + c) * Hn + y) * Wn;
        float g[8];
        #pragma unroll
        for (int j = 0; j < 8; ++j) g[j] = gath1(rrow, xs[j]);
        uint4 pk;
        pk.x = packbf(g[0], g[1]);
        pk.y = packbf(g[2], g[3]);
        pk.z = packbf(g[4], g[5]);
        pk.w = packbf(g[6], g[7]);
        *(uint4*)(wbf + (size_t)c * PLANE + rowoff + x0) = pk;
    }

    #pragma unroll
    for (int off = 32; off > 0; off >>= 1) {
        vsum += __shfl_down(vsum, off);
        lsum += __shfl_down(lsum, off);
    }
    int lane = t & 63, wv = t >> 6;
    if (lane == 0) { red[0][wv] = vsum; red[1][wv] = lsum; }
    __syncthreads();
    if (t == 0) {
        float V = 0.f, L = 0.f;
        #pragma unroll
        for (int i = 0; i < TPB / 64; ++i) { V += red[0][i]; L += red[1][i]; }
        red1[2 * blockIdx.x + 0] = V;
        red1[2 * blockIdx.x + 1] = L;
    }
}

// ---- Pass 2: 3x3 SSIM + L1, 8 cols x 3 channels per thread; per-block p slot ----
__global__ __launch_bounds__(TPB) void pass_ssim(
    const float* __restrict__ left, const unsigned short* __restrict__ wbf,
    const float* __restrict__ vwp, float* __restrict__ red2)
{
    __shared__ float red[TPB / 64];
    const int t = threadIdx.x;
    int flat = blockIdx.x * TPB + t;
    int xq = flat % CH8;
    int rest = flat / CH8;
    int y = rest % Hn;
    int b = rest / Hn;
    int x0 = xq * 8;

    const float ml = (x0 > 0) ? 1.f : 0.f;
    const float mr = (x0 + 8 < Wn) ? 1.f : 0.f;
    const int xm1 = max(x0 - 1, 0);
    const int xp8 = min(x0 + 8, Wn - 1);
    const bool yint = (y > 0 && y < Hn - 1);

    float inv_cy = yint ? (1.f / 3.f) : 0.5f;
    float invj[8];
    #pragma unroll
    for (int j = 0; j < 8; ++j) {
        int xg = x0 + j;
        invj[j] = inv_cy * ((xg == 0 || xg == Wn - 1) ? 0.5f : (1.f / 3.f));
    }
    size_t vrow = ((size_t)b * Hn + y) * Wn + x0;
    float4 v4a = *(const float4*)(vwp + vrow);
    float4 v4b = *(const float4*)(vwp + vrow + 4);
    float vws[8] = {v4a.x, v4a.y, v4a.z, v4a.w, v4b.x, v4b.y, v4b.z, v4b.w};

    float psum = 0.f;
    #pragma unroll
    for (int c = 0; c < Cn; ++c) {
        const float* lch = left + ((size_t)(b * Cn + c)) * Hn * Wn;
        const unsigned short* wch = wbf + (size_t)c * PLANE + (size_t)b * Hn * Wn;

        float cx[10], cy[10], cxx[10], cyy[10], cxy[10];
        float lc[8], wc[8];               // row-1 centers for the L1 term

        #pragma unroll
        for (int r = 0; r < 3; ++r) {
            float lv[10], wv[10];
            if (yint) {                   // wave-uniform fast path
                const float* lr_ = lch + (size_t)(y - 1 + r) * Wn;
                const unsigned short* wr_ = wch + (size_t)(y - 1 + r) * Wn;
                float4 lm0 = *(const float4*)(lr_ + x0);
                float4 lm1 = *(const float4*)(lr_ + x0 + 4);
                uint4 wm = *(const uint4*)(wr_ + x0);
                lv[0] = lr_[xm1] * ml;
                lv[1] = lm0.x; lv[2] = lm0.y; lv[3] = lm0.z; lv[4] = lm0.w;
                lv[5] = lm1.x; lv[6] = lm1.y; lv[7] = lm1.z; lv[8] = lm1.w;
                lv[9] = lr_[xp8] * mr;
                wv[0] = bf2f(wr_[xm1]) * ml;
                wv[1] = __uint_as_float(wm.x << 16);
                wv[2] = __uint_as_float(wm.x & 0xffff0000u);
                wv[3] = __uint_as_float(wm.y << 16);
                wv[4] = __uint_as_float(wm.y & 0xffff0000u);
                wv[5] = __uint_as_float(wm.z << 16);
                wv[6] = __uint_as_float(wm.z & 0xffff0000u);
                wv[7] = __uint_as_float(wm.w << 16);
                wv[8] = __uint_as_float(wm.w & 0xffff0000u);
                wv[9] = bf2f(wr_[xp8]) * mr;
            } else {                      // border rows: mask + clamp
                int yy = y - 1 + r;
                float ym = (yy >= 0 && yy < Hn) ? 1.f : 0.f;
                int ycl = min(max(yy, 0), Hn - 1);
                const float* lr_ = lch + (size_t)ycl * Wn;
                const unsigned short* wr_ = wch + (size_t)ycl * Wn;
                float4 lm0 = *(const float4*)(lr_ + x0);
                float4 lm1 = *(const float4*)(lr_ + x0 + 4);
                uint4 wm = *(const uint4*)(wr_ + x0);
                lv[0] = lr_[xm1] * (ym * ml);
                lv[1] = lm0.x * ym; lv[2] = lm0.y * ym; lv[3] = lm0.z * ym; lv[4] = lm0.w * ym;
                lv[5] = lm1.x * ym; lv[6] = lm1.y * ym; lv[7] = lm1.z * ym; lv[8] = lm1.w * ym;
                lv[9] = lr_[xp8] * (ym * mr);
                wv[0] = bf2f(wr_[xm1]) * (ym * ml);
                wv[1] = __uint_as_float(wm.x << 16) * ym;
                wv[2] = __uint_as_float(wm.x & 0xffff0000u) * ym;
                wv[3] = __uint_as_float(wm.y << 16) * ym;
                wv[4] = __uint_as_float(wm.y & 0xffff0000u) * ym;
                wv[5] = __uint_as_float(wm.z << 16) * ym;
                wv[6] = __uint_as_float(wm.z & 0xffff0000u) * ym;
                wv[7] = __uint_as_float(wm.w << 16) * ym;
                wv[8] = __uint_as_float(wm.w & 0xffff0000u) * ym;
                wv[9] = bf2f(wr_[xp8]) * (ym * mr);
            }
            if (r == 0) {
                #pragma unroll
                for (int q = 0; q < 10; ++q) {
                    float lq = lv[q], wq = wv[q];
                    cx[q] = lq; cy[q] = wq;
                    cxx[q] = lq * lq; cyy[q] = wq * wq; cxy[q] = lq * wq;
                }
            } else {
                #pragma unroll
                for (int q = 0; q < 10; ++q) {
                    float lq = lv[q], wq = wv[q];
                    cx[q] += lq; cy[q] += wq;
                    cxx[q] = fmaf(lq, lq, cxx[q]);
                    cyy[q] = fmaf(wq, wq, cyy[q]);
                    cxy[q] = fmaf(lq, wq, cxy[q]);
                }
                if (r == 1) {
                    #pragma unroll
                    for (int j = 0; j < 8; ++j) { lc[j] = lv[j + 1]; wc[j] = wv[j + 1]; }
                }
            }
        }

        #pragma unroll
        for (int j = 0; j < 8; ++j) {
            float Sx  = cx[j]  + cx[j + 1]  + cx[j + 2];
            float Sy  = cy[j]  + cy[j + 1]  + cy[j + 2];
            float Sxx = cxx[j] + cxx[j + 1] + cxx[j + 2];
            float Syy = cyy[j] + cyy[j + 1] + cyy[j + 2];
            float Sxy = cxy[j] + cxy[j + 1] + cxy[j + 2];
            float inv = invj[j];
            float mu_x = Sx * inv, mu_y = Sy * inv;
            float sig_x  = Sxx * inv - mu_x * mu_x;
            float sig_y  = Syy * inv - mu_y * mu_y;
            float sig_xy = Sxy * inv - mu_x * mu_y;
            float num = (2.f * mu_x * mu_y + kC1) * (2.f * sig_xy + kC2);
            float den = (mu_x * mu_x + mu_y * mu_y + kC1) * (sig_x + sig_y + kC2);
            float ssim = num * __builtin_amdgcn_rcpf(den + 1e-12f);
            float sm = fminf(fmaxf(0.5f * (1.f - ssim), 0.f), 1.f);
            float df = lc[j] - wc[j];
            float l1v = __builtin_amdgcn_sqrtf(df * df + kEps2);
            psum += (A3 * sm + B3 * l1v) * vws[j];
        }
    }

    #pragma unroll
    for (int off = 32; off > 0; off >>= 1) psum += __shfl_down(psum, off);
    int lane = t & 63, wv = t >> 6;
    if (lane == 0) red[wv] = psum;
    __syncthreads();
    if (t == 0) {
        float P = 0.f;
        #pragma unroll
        for (int i = 0; i < TPB / 64; ++i) P += red[i];
        red2[blockIdx.x] = P;
    }
}

// ---- Pass 3: single-block reduction over slots + finalize ----
__global__ __launch_bounds__(1024) void pass_reduce(
    const float* __restrict__ red1, const float* __restrict__ red2,
    float* __restrict__ out)
{
    __shared__ float sm[3][16];
    const int t = threadIdx.x;
    float V = 0.f, L = 0.f, P = 0.f;
    for (int i = t; i < NBLK1; i += 1024) {
        V += red1[2 * i + 0];
        L += red1[2 * i + 1];
    }
    for (int i = t; i < NBLK2; i += 1024) P += red2[i];
    #pragma unroll
    for (int off = 32; off > 0; off >>= 1) {
        V += __shfl_down(V, off);
        L += __shfl_down(L, off);
        P += __shfl_down(P, off);
    }
    int lane = t & 63, wv = t >> 6;
    if (lane == 0) { sm[0][wv] = V; sm[1][wv] = L; sm[2][wv] = P; }
    __syncthreads();
    if (t == 0) {
        float Va = 0.f, La = 0.f, Pa = 0.f;
        #pragma unroll
        for (int i = 0; i < 16; ++i) { Va += sm[0][i]; La += sm[1][i]; Pa += sm[2][i]; }
        float photo = Pa / (Va + 1e-6f);
        float lr = La / (Va + 1e-6f);
        out[0] = photo + 0.2f * lr;   // W_PHOTO=1, W_LR=0.2
        out[1] = photo;
        out[2] = lr;
        out[3] = Va * (1.f / (float)(Bn * Hn * Wn));
    }
}

// ---- Fallback (fused, only if ws too small) --------------------------------
namespace fb {
constexpr int RS = 8, SR = RS + 2, CW = 256, SC = CW + 2;
constexpr int NBX = (Wn + CW - 1) / CW, NSTRIP = Hn / RS;
constexpr int NBLK = NBX * NSTRIP * Bn;
}

__global__ __launch_bounds__(TPB) void stereo_fallback(
    const float* __restrict__ left, const float* __restrict__ right,
    const float* __restrict__ d_left, const float* __restrict__ d_right,
    const float* __restrict__ nonocc, float* __restrict__ acc,
    float* __restrict__ out)
{
    using namespace fb;
    __shared__ float sW[SR][SC];
    __shared__ float red[3][TPB / 64];
    const int t = threadIdx.x;
    const int bx = blockIdx.x, strip = blockIdx.y, b = blockIdx.z;
    const int y0 = strip * RS;
    const int x = bx * CW + t;
    const bool inb = (x < Wn);
    const int xc = min(x, Wn - 1);
    const float* leftB  = left   + (size_t)b * Cn * Hn * Wn;
    const float* rightB = right  + (size_t)b * Cn * Hn * Wn;
    const float* dL = d_left  + (size_t)b * Hn * Wn;
    const float* dR = d_right + (size_t)b * Hn * Wn;
    const float* no = nonocc  + (size_t)b * Hn * Wn;

    float vw_r[RS];
    float p_sum = 0.f, v_sum = 0.f, l_sum = 0.f;
    #pragma unroll
    for (int k = 0; k < RS; ++k) {
        int y = y0 + k;
        float d = dL[y * Wn + xc];
        float xs = (float)x - d;
        float gx = 2.f * xs / (float)(Wn - 1) - 1.f;
        float vmask = (inb && gx >= -1.f && gx <= 1.f) ? 1.f : 0.f;
        float vw = vmask * no[y * Wn + xc];
        vw_r[k] = vw; v_sum += vw;
        float drw = gath1(dR + (size_t)y * Wn, xs);
        float dd = d - drw;
        l_sum += sqrtf(dd * dd + kEps2) * vw;
    }
    const float xm_l = (x > 0) ? 1.f : 0.f;
    const float xm_r = (x < Wn - 1) ? 1.f : 0.f;
    const int xl = max(x - 1, 0), xr = min(x + 1, Wn - 1);
    const float inv_cx = (x == 0 || x == Wn - 1) ? 0.5f : (1.f / 3.f);
    const int g0 = bx * CW - 1;
    #pragma unroll
    for (int c = 0; c < Cn; ++c) {
        __syncthreads();
        const float* rchan = rightB + (size_t)c * Hn * Wn;
        #pragma unroll
        for (int r = 0; r < SR; ++r) {
            int y = y0 - 1 + r;
            bool yok = (y >= 0 && y < Hn);
            int g = g0 + t;
            float wv = 0.f;
            if (yok && g >= 0 && g < Wn)
                wv = gath1(rchan + (size_t)y * Wn, (float)g - dL[y * Wn + g]);
            sW[r][t] = wv;
            if (t < 2) {
                g = g0 + CW + t;
                wv = 0.f;
                if (yok && g >= 0 && g < Wn)
                    wv = gath1(rchan + (size_t)y * Wn, (float)g - dL[y * Wn + g]);
                sW[r][CW + t] = wv;
            }
        }
        __syncthreads();
        const float* lchan = leftB + (size_t)c * Hn * Wn;
        float lA[3][3], wA[3][3];
        #pragma unroll
        for (int r = 0; r < 2; ++r) {
            int y = y0 - 1 + r;
            int yy = min(max(y, 0), Hn - 1);
            float ym = (y >= 0 && y < Hn) ? 1.f : 0.f;
            const float* lrow = lchan + (size_t)yy * Wn;
            lA[r][0] = lrow[xl] * (ym * xm_l);
            lA[r][1] = lrow[xc] * ym;
            lA[r][2] = lrow[xr] * (ym * xm_r);
            wA[r][0] = sW[r][t]; wA[r][1] = sW[r][t + 1]; wA[r][2] = sW[r][t + 2];
        }
        #pragma unroll
        for (int k = 0; k < RS; ++k) {
            const int rn = k + 2, sn = rn % 3;
            int y = y0 - 1 + rn;
            int yy = min(max(y, 0), Hn - 1);
            float ym = (y >= 0 && y < Hn) ? 1.f : 0.f;
            const float* lrow = lchan + (size_t)yy * Wn;
            lA[sn][0] = lrow[xl] * (ym * xm_l);
            lA[sn][1] = lrow[xc] * ym;
            lA[sn][2] = lrow[xr] * (ym * xm_r);
            wA[sn][0] = sW[rn][t]; wA[sn][1] = sW[rn][t + 1]; wA[sn][2] = sW[rn][t + 2];
            float Sx = 0.f, Sy = 0.f, Sxx = 0.f, Syy = 0.f, Sxy = 0.f;
            #pragma unroll
            for (int s = 0; s < 3; ++s)
                #pragma unroll
                for (int j = 0; j < 3; ++j) {
                    float lv = lA[s][j], wv = wA[s][j];
                    Sx += lv; Sy += wv;
                    Sxx = fmaf(lv, lv, Sxx); Syy = fmaf(wv, wv, Syy); Sxy = fmaf(lv, wv, Sxy);
                }
            int yo = y0 + k;
            float inv = ((yo == 0 || yo == Hn - 1) ? 0.5f : (1.f / 3.f)) * inv_cx;
            float mu_x = Sx * inv, mu_y = Sy * inv;
            float sig_x = Sxx * inv - mu_x * mu_x;
            float sig_y = Syy * inv - mu_y * mu_y;
            float sig_xy = Sxy * inv - mu_x * mu_y;
            float num = (2.f * mu_x * mu_y + kC1) * (2.f * sig_xy + kC2);
            float den = (mu_x * mu_x + mu_y * mu_y + kC1) * (sig_x + sig_y + kC2);
            float ssim = num / (den + 1e-12f);
            float sm = fminf(fmaxf(0.5f * (1.f - ssim), 0.f), 1.f);
            int sc2 = (k + 1) % 3;
            float df = lA[sc2][1] - wA[sc2][1];
            p_sum += (A3 * sm + B3 * sqrtf(df * df + kEps2)) * vw_r[k];
        }
    }
    #pragma unroll
    for (int off = 32; off > 0; off >>= 1) {
        p_sum += __shfl_down(p_sum, off);
        v_sum += __shfl_down(v_sum, off);
        l_sum += __shfl_down(l_sum, off);
    }
    int lane = t & 63, wvi = t >> 6;
    if (lane == 0) { red[0][wvi] = p_sum; red[1][wvi] = v_sum; red[2][wvi] = l_sum; }
    __syncthreads();
    if (t == 0) {
        float P = 0.f, V = 0.f, L = 0.f;
        #pragma unroll
        for (int i = 0; i < TPB / 64; ++i) { P += red[0][i]; V += red[1][i]; L += red[2][i]; }
        atomicAdd(&acc[0], P);
        atomicAdd(&acc[1], V);
        atomicAdd(&acc[2], L);
        __threadfence();
        unsigned prev = atomicAdd((unsigned*)&acc[3], 1u);
        if (prev == fb::NBLK - 1) {
            float Pa = atomicAdd(&acc[0], 0.f);
            float Va = atomicAdd(&acc[1], 0.f);
            float La = atomicAdd(&acc[2], 0.f);
            float photo = Pa / (Va + 1e-6f);
            float lr = La / (Va + 1e-6f);
            out[0] = photo + 0.2f * lr;
            out[1] = photo;
            out[2] = lr;
            out[3] = Va * (1.f / (float)(Bn * Hn * Wn));
        }
    }
}

extern "C" void kernel_launch(void* const* d_in, const int* in_sizes, int n_in,
                              void* d_out, int out_size, void* d_ws, size_t ws_size,
                              hipStream_t stream) {
    const float* left   = (const float*)d_in[0];
    const float* right  = (const float*)d_in[1];
    const float* dl     = (const float*)d_in[2];
    const float* dr     = (const float*)d_in[3];
    const float* nonocc = (const float*)d_in[4];
    float* ws = (float*)d_ws;
    float* out = (float*)d_out;

    if (ws_size >= WS_NEED) {
        float* red1 = ws + RED1_OFF;
        float* red2 = ws + RED2_OFF;
        unsigned short* wbf = (unsigned short*)(ws + BF_OFF);
        float* vwp = ws + VW_OFF;
        pass_warp<<<NBLK1, TPB, 0, stream>>>(right, dl, dr, nonocc, wbf, vwp, red1);
        pass_ssim<<<NBLK2, TPB, 0, stream>>>(left, wbf, vwp, red2);
        pass_reduce<<<1, 1024, 0, stream>>>(red1, red2, out);
    } else {
        hipMemsetAsync(ws, 0, 4 * sizeof(float), stream);
        dim3 grid(fb::NBX, fb::NSTRIP, Bn);
        stereo_fallback<<<grid, TPB, 0, stream>>>(left, right, dl, dr, nonocc, ws, out);
    }
}

// Round 12
// 206.203 us; speedup vs baseline: 1.1087x; 1.1087x over previous
//
#include <hip/hip_runtime.h>
#include <math.h>

namespace {
constexpr int Bn = 8, Cn = 3, Hn = 512, Wn = 960;
constexpr int TPB = 256;
constexpr int CH4 = Wn / 4;                     // 240 float4 chunks per row
constexpr int NBLK1 = Bn * Hn * CH4 / TPB;      // 3840 (pass_warp blocks)
constexpr int NBLK2 = Bn * Hn * CH4 / TPB;      // 3840 (pass_ssim blocks, channel-looped)
constexpr size_t PLANE = (size_t)Bn * Hn * Wn;  // 3,932,160 px
// ws float layout: pad16 | red1 2*NBLK1 | red2 NBLK2 | bf16 planes (3*PLANE ushort) | vw plane (PLANE f32)
constexpr size_t RED1_OFF = 16;
constexpr size_t RED2_OFF = RED1_OFF + 2 * (size_t)NBLK1;   // 7696
constexpr size_t BF_OFF   = RED2_OFF + (size_t)NBLK2;       // 11536 floats (16B aligned)
constexpr size_t VW_OFF   = BF_OFF + (3 * PLANE) / 2;       // floats (16B aligned)
constexpr size_t WS_NEED  = (VW_OFF + PLANE) * sizeof(float);
constexpr float kC1 = 1e-4f;        // 0.01^2
constexpr float kC2 = 9e-4f;        // 0.03^2
constexpr float kEps2 = 1e-6f;      // 0.001^2
constexpr float A3 = 0.85f / 3.f;   // alpha/3
constexpr float B3 = 0.05f;         // (1-alpha)/3
}

__device__ __forceinline__ float gath1(const float* __restrict__ row, float xs) {
    float xf = floorf(xs);
    float wx = xs - xf;
    int xi = (int)xf;
    int a0 = min(max(xi, 0), Wn - 1);
    int a1 = min(max(xi + 1, 0), Wn - 1);
    return (1.f - wx) * row[a0] + wx * row[a1];
}

__device__ __forceinline__ unsigned short f2bf(float f) {   // RTNE
    unsigned u = __float_as_uint(f);
    u += 0x7fffu + ((u >> 16) & 1u);
    return (unsigned short)(u >> 16);
}
__device__ __forceinline__ float bf2f(unsigned short h) {
    return __uint_as_float(((unsigned)h) << 16);
}

// ---- Pass 1: warp right -> bf16 planes; vw plane (f32); per-block (v,l) slots ----
__global__ __launch_bounds__(TPB) void pass_warp(
    const float* __restrict__ right, const float* __restrict__ d_left,
    const float* __restrict__ d_right, const float* __restrict__ nonocc,
    unsigned short* __restrict__ wbf, float* __restrict__ vwp,
    float* __restrict__ red1)
{
    __shared__ float red[2][TPB / 64];
    const int t = threadIdx.x;
    int flat = blockIdx.x * TPB + t;
    int xq = flat % CH4;
    int rest = flat / CH4;
    int y = rest % Hn;
    int b = rest / Hn;
    int x0 = xq * 4;
    size_t rowoff = ((size_t)b * Hn + y) * Wn;

    float4 d4 = *(const float4*)(d_left + rowoff + x0);
    float4 n4 = *(const float4*)(nonocc + rowoff + x0);
    float ds[4] = {d4.x, d4.y, d4.z, d4.w};
    float ns[4] = {n4.x, n4.y, n4.z, n4.w};
    float xs[4], vw[4];
    float vsum = 0.f, lsum = 0.f;
    const float* drow = d_right + rowoff;
    #pragma unroll
    for (int j = 0; j < 4; ++j) {
        xs[j] = (float)(x0 + j) - ds[j];
        // gx in [-1,1]  <=>  xs in [0, W-1]
        float vm = (xs[j] >= 0.f && xs[j] <= (float)(Wn - 1)) ? 1.f : 0.f;
        vw[j] = vm * ns[j];
        vsum += vw[j];
        float drw = gath1(drow, xs[j]);
        float dd = ds[j] - drw;
        lsum += __builtin_amdgcn_sqrtf(dd * dd + kEps2) * vw[j];
    }
    *(float4*)(vwp + rowoff + x0) = float4{vw[0], vw[1], vw[2], vw[3]};

    #pragma unroll
    for (int c = 0; c < Cn; ++c) {
        const float* rrow = right + ((size_t)(b * Cn + c) * Hn + y) * Wn;
        ushort4 wv;
        wv.x = f2bf(gath1(rrow, xs[0]));
        wv.y = f2bf(gath1(rrow, xs[1]));
        wv.z = f2bf(gath1(rrow, xs[2]));
        wv.w = f2bf(gath1(rrow, xs[3]));
        *(ushort4*)(wbf + (size_t)c * PLANE + rowoff + x0) = wv;
    }

    #pragma unroll
    for (int off = 32; off > 0; off >>= 1) {
        vsum += __shfl_down(vsum, off);
        lsum += __shfl_down(lsum, off);
    }
    int lane = t & 63, wv = t >> 6;
    if (lane == 0) { red[0][wv] = vsum; red[1][wv] = lsum; }
    __syncthreads();
    if (t == 0) {
        float V = 0.f, L = 0.f;
        #pragma unroll
        for (int i = 0; i < TPB / 64; ++i) { V += red[0][i]; L += red[1][i]; }
        red1[2 * blockIdx.x + 0] = V;
        red1[2 * blockIdx.x + 1] = L;
    }
}

// ---- Pass 2: 3x3 SSIM + L1, all channels per thread; per-block p slot ----
__global__ __launch_bounds__(TPB) void pass_ssim(
    const float* __restrict__ left, const unsigned short* __restrict__ wbf,
    const float* __restrict__ vwp, float* __restrict__ red2)
{
    __shared__ float red[TPB / 64];
    const int t = threadIdx.x;
    int flat = blockIdx.x * TPB + t;
    int xq = flat % CH4;
    int rest = flat / CH4;
    int y = rest % Hn;
    int b = rest / Hn;
    int x0 = xq * 4;

    const float ml = (x0 > 0) ? 1.f : 0.f;
    const float mr = (x0 + 4 < Wn) ? 1.f : 0.f;
    const int xm1 = max(x0 - 1, 0);
    const int xp4 = min(x0 + 4, Wn - 1);
    const bool yint = (y > 0 && y < Hn - 1);

    float inv_cy = yint ? (1.f / 3.f) : 0.5f;
    float invj[4];
    #pragma unroll
    for (int j = 0; j < 4; ++j) {
        int xg = x0 + j;
        invj[j] = inv_cy * ((xg == 0 || xg == Wn - 1) ? 0.5f : (1.f / 3.f));
    }
    float4 v4 = *(const float4*)(vwp + ((size_t)b * Hn + y) * Wn + x0);
    float vws[4] = {v4.x, v4.y, v4.z, v4.w};

    float psum = 0.f;
    #pragma unroll
    for (int c = 0; c < Cn; ++c) {
        const float* lch = left + ((size_t)(b * Cn + c)) * Hn * Wn;
        const unsigned short* wch = wbf + (size_t)c * PLANE + (size_t)b * Hn * Wn;

        float l[3][6], w[3][6];
        if (yint) {                      // fast path: all 3 rows in-bounds
            #pragma unroll
            for (int r = 0; r < 3; ++r) {
                const float* lr_ = lch + (size_t)(y - 1 + r) * Wn;
                const unsigned short* wr_ = wch + (size_t)(y - 1 + r) * Wn;
                float4 lm = *(const float4*)(lr_ + x0);
                ushort4 wm = *(const ushort4*)(wr_ + x0);
                l[r][0] = lr_[xm1] * ml;
                l[r][1] = lm.x; l[r][2] = lm.y; l[r][3] = lm.z; l[r][4] = lm.w;
                l[r][5] = lr_[xp4] * mr;
                w[r][0] = bf2f(wr_[xm1]) * ml;
                w[r][1] = bf2f(wm.x); w[r][2] = bf2f(wm.y);
                w[r][3] = bf2f(wm.z); w[r][4] = bf2f(wm.w);
                w[r][5] = bf2f(wr_[xp4]) * mr;
            }
        } else {                          // border rows: mask + clamp
            #pragma unroll
            for (int r = 0; r < 3; ++r) {
                int yy = y - 1 + r;
                float ym = (yy >= 0 && yy < Hn) ? 1.f : 0.f;
                int ycl = min(max(yy, 0), Hn - 1);
                const float* lr_ = lch + (size_t)ycl * Wn;
                const unsigned short* wr_ = wch + (size_t)ycl * Wn;
                float4 lm = *(const float4*)(lr_ + x0);
                ushort4 wm = *(const ushort4*)(wr_ + x0);
                l[r][0] = lr_[xm1] * (ym * ml);
                l[r][1] = lm.x * ym; l[r][2] = lm.y * ym;
                l[r][3] = lm.z * ym; l[r][4] = lm.w * ym;
                l[r][5] = lr_[xp4] * (ym * mr);
                w[r][0] = bf2f(wr_[xm1]) * (ym * ml);
                w[r][1] = bf2f(wm.x) * ym; w[r][2] = bf2f(wm.y) * ym;
                w[r][3] = bf2f(wm.z) * ym; w[r][4] = bf2f(wm.w) * ym;
                w[r][5] = bf2f(wr_[xp4]) * (ym * mr);
            }
        }

        float cx[6], cy[6], cxx[6], cyy[6], cxy[6];
        #pragma unroll
        for (int q = 0; q < 6; ++q) {
            float l0 = l[0][q], l1 = l[1][q], l2 = l[2][q];
            float w0 = w[0][q], w1 = w[1][q], w2 = w[2][q];
            cx[q] = l0 + l1 + l2;
            cy[q] = w0 + w1 + w2;
            cxx[q] = fmaf(l0, l0, fmaf(l1, l1, l2 * l2));
            cyy[q] = fmaf(w0, w0, fmaf(w1, w1, w2 * w2));
            cxy[q] = fmaf(l0, w0, fmaf(l1, w1, l2 * w2));
        }

        #pragma unroll
        for (int j = 0; j < 4; ++j) {
            float Sx  = cx[j]  + cx[j + 1]  + cx[j + 2];
            float Sy  = cy[j]  + cy[j + 1]  + cy[j + 2];
            float Sxx = cxx[j] + cxx[j + 1] + cxx[j + 2];
            float Syy = cyy[j] + cyy[j + 1] + cyy[j + 2];
            float Sxy = cxy[j] + cxy[j + 1] + cxy[j + 2];
            float inv = invj[j];
            float mu_x = Sx * inv, mu_y = Sy * inv;
            float sig_x  = Sxx * inv - mu_x * mu_x;
            float sig_y  = Syy * inv - mu_y * mu_y;
            float sig_xy = Sxy * inv - mu_x * mu_y;
            float num = (2.f * mu_x * mu_y + kC1) * (2.f * sig_xy + kC2);
            float den = (mu_x * mu_x + mu_y * mu_y + kC1) * (sig_x + sig_y + kC2);
            float ssim = num * __builtin_amdgcn_rcpf(den + 1e-12f);
            float sm = fminf(fmaxf(0.5f * (1.f - ssim), 0.f), 1.f);
            float df = l[1][j + 1] - w[1][j + 1];
            float l1v = __builtin_amdgcn_sqrtf(df * df + kEps2);
            psum = fmaf(fmaf(A3, sm, B3 * l1v), vws[j], psum);
        }
    }

    #pragma unroll
    for (int off = 32; off > 0; off >>= 1) psum += __shfl_down(psum, off);
    int lane = t & 63, wv = t >> 6;
    if (lane == 0) red[wv] = psum;
    __syncthreads();
    if (t == 0) {
        float P = 0.f;
        #pragma unroll
        for (int i = 0; i < TPB / 64; ++i) P += red[i];
        red2[blockIdx.x] = P;
    }
}

// ---- Pass 3: single-block reduction over slots + finalize ----
__global__ __launch_bounds__(1024) void pass_reduce(
    const float* __restrict__ red1, const float* __restrict__ red2,
    float* __restrict__ out)
{
    __shared__ float sm[3][16];
    const int t = threadIdx.x;
    float V = 0.f, L = 0.f, P = 0.f;
    for (int i = t; i < NBLK1; i += 1024) {
        V += red1[2 * i + 0];
        L += red1[2 * i + 1];
    }
    for (int i = t; i < NBLK2; i += 1024) P += red2[i];
    #pragma unroll
    for (int off = 32; off > 0; off >>= 1) {
        V += __shfl_down(V, off);
        L += __shfl_down(L, off);
        P += __shfl_down(P, off);
    }
    int lane = t & 63, wv = t >> 6;
    if (lane == 0) { sm[0][wv] = V; sm[1][wv] = L; sm[2][wv] = P; }
    __syncthreads();
    if (t == 0) {
        float Va = 0.f, La = 0.f, Pa = 0.f;
        #pragma unroll
        for (int i = 0; i < 16; ++i) { Va += sm[0][i]; La += sm[1][i]; Pa += sm[2][i]; }
        float photo = Pa / (Va + 1e-6f);
        float lr = La / (Va + 1e-6f);
        out[0] = photo + 0.2f * lr;   // W_PHOTO=1, W_LR=0.2
        out[1] = photo;
        out[2] = lr;
        out[3] = Va * (1.f / (float)(Bn * Hn * Wn));
    }
}

// ---- Fallback (fused, only if ws too small) --------------------------------
namespace fb {
constexpr int RS = 8, SR = RS + 2, CW = 256, SC = CW + 2;
constexpr int NBX = (Wn + CW - 1) / CW, NSTRIP = Hn / RS;
constexpr int NBLK = NBX * NSTRIP * Bn;
}

__global__ __launch_bounds__(TPB) void stereo_fallback(
    const float* __restrict__ left, const float* __restrict__ right,
    const float* __restrict__ d_left, const float* __restrict__ d_right,
    const float* __restrict__ nonocc, float* __restrict__ acc,
    float* __restrict__ out)
{
    using namespace fb;
    __shared__ float sW[SR][SC];
    __shared__ float red[3][TPB / 64];
    const int t = threadIdx.x;
    const int bx = blockIdx.x, strip = blockIdx.y, b = blockIdx.z;
    const int y0 = strip * RS;
    const int x = bx * CW + t;
    const bool inb = (x < Wn);
    const int xc = min(x, Wn - 1);
    const float* leftB  = left   + (size_t)b * Cn * Hn * Wn;
    const float* rightB = right  + (size_t)b * Cn * Hn * Wn;
    const float* dL = d_left  + (size_t)b * Hn * Wn;
    const float* dR = d_right + (size_t)b * Hn * Wn;
    const float* no = nonocc  + (size_t)b * Hn * Wn;

    float vw_r[RS];
    float p_sum = 0.f, v_sum = 0.f, l_sum = 0.f;
    #pragma unroll
    for (int k = 0; k < RS; ++k) {
        int y = y0 + k;
        float d = dL[y * Wn + xc];
        float xs = (float)x - d;
        float vmask = (inb && xs >= 0.f && xs <= (float)(Wn - 1)) ? 1.f : 0.f;
        float vw = vmask * no[y * Wn + xc];
        vw_r[k] = vw; v_sum += vw;
        float drw = gath1(dR + (size_t)y * Wn, xs);
        float dd = d - drw;
        l_sum += sqrtf(dd * dd + kEps2) * vw;
    }
    const float xm_l = (x > 0) ? 1.f : 0.f;
    const float xm_r = (x < Wn - 1) ? 1.f : 0.f;
    const int xl = max(x - 1, 0), xr = min(x + 1, Wn - 1);
    const float inv_cx = (x == 0 || x == Wn - 1) ? 0.5f : (1.f / 3.f);
    const int g0 = bx * CW - 1;
    #pragma unroll
    for (int c = 0; c < Cn; ++c) {
        __syncthreads();
        const float* rchan = rightB + (size_t)c * Hn * Wn;
        #pragma unroll
        for (int r = 0; r < SR; ++r) {
            int y = y0 - 1 + r;
            bool yok = (y >= 0 && y < Hn);
            int g = g0 + t;
            float wv = 0.f;
            if (yok && g >= 0 && g < Wn)
                wv = gath1(rchan + (size_t)y * Wn, (float)g - dL[y * Wn + g]);
            sW[r][t] = wv;
            if (t < 2) {
                g = g0 + CW + t;
                wv = 0.f;
                if (yok && g >= 0 && g < Wn)
                    wv = gath1(rchan + (size_t)y * Wn, (float)g - dL[y * Wn + g]);
                sW[r][CW + t] = wv;
            }
        }
        __syncthreads();
        const float* lchan = leftB + (size_t)c * Hn * Wn;
        float lA[3][3], wA[3][3];
        #pragma unroll
        for (int r = 0; r < 2; ++r) {
            int y = y0 - 1 + r;
            int yy = min(max(y, 0), Hn - 1);
            float ym = (y >= 0 && y < Hn) ? 1.f : 0.f;
            const float* lrow = lchan + (size_t)yy * Wn;
            lA[r][0] = lrow[xl] * (ym * xm_l);
            lA[r][1] = lrow[xc] * ym;
            lA[r][2] = lrow[xr] * (ym * xm_r);
            wA[r][0] = sW[r][t]; wA[r][1] = sW[r][t + 1]; wA[r][2] = sW[r][t + 2];
        }
        #pragma unroll
        for (int k = 0; k < RS; ++k) {
            const int rn = k + 2, sn = rn % 3;
            int y = y0 - 1 + rn;
            int yy = min(max(y, 0), Hn - 1);
            float ym = (y >= 0 && y < Hn) ? 1.f : 0.f;
            const float* lrow = lchan + (size_t)yy * Wn;
            lA[sn][0] = lrow[xl] * (ym * xm_l);
            lA[sn][1] = lrow[xc] * ym;
            lA[sn][2] = lrow[xr] * (ym * xm_r);
            wA[sn][0] = sW[rn][t]; wA[sn][1] = sW[rn][t + 1]; wA[sn][2] = sW[rn][t + 2];
            float Sx = 0.f, Sy = 0.f, Sxx = 0.f, Syy = 0.f, Sxy = 0.f;
            #pragma unroll
            for (int s = 0; s < 3; ++s)
                #pragma unroll
                for (int j = 0; j < 3; ++j) {
                    float lv = lA[s][j], wv = wA[s][j];
                    Sx += lv; Sy += wv;
                    Sxx = fmaf(lv, lv, Sxx); Syy = fmaf(wv, wv, Syy); Sxy = fmaf(lv, wv, Sxy);
                }
            int yo = y0 + k;
            float inv = ((yo == 0 || yo == Hn - 1) ? 0.5f : (1.f / 3.f)) * inv_cx;
            float mu_x = Sx * inv, mu_y = Sy * inv;
            float sig_x = Sxx * inv - mu_x * mu_x;
            float sig_y = Syy * inv - mu_y * mu_y;
            float sig_xy = Sxy * inv - mu_x * mu_y;
            float num = (2.f * mu_x * mu_y + kC1) * (2.f * sig_xy + kC2);
            float den = (mu_x * mu_x + mu_y * mu_y + kC1) * (sig_x + sig_y + kC2);
            float ssim = num / (den + 1e-12f);
            float sm = fminf(fmaxf(0.5f * (1.f - ssim), 0.f), 1.f);
            int sc2 = (k + 1) % 3;
            float df = lA[sc2][1] - wA[sc2][1];
            p_sum += (A3 * sm + B3 * sqrtf(df * df + kEps2)) * vw_r[k];
        }
    }
    #pragma unroll
    for (int off = 32; off > 0; off >>= 1) {
        p_sum += __shfl_down(p_sum, off);
        v_sum += __shfl_down(v_sum, off);
        l_sum += __shfl_down(l_sum, off);
    }
    int lane = t & 63, wvi = t >> 6;
    if (lane == 0) { red[0][wvi] = p_sum; red[1][wvi] = v_sum; red[2][wvi] = l_sum; }
    __syncthreads();
    if (t == 0) {
        float P = 0.f, V = 0.f, L = 0.f;
        #pragma unroll
        for (int i = 0; i < TPB / 64; ++i) { P += red[0][i]; V += red[1][i]; L += red[2][i]; }
        atomicAdd(&acc[0], P);
        atomicAdd(&acc[1], V);
        atomicAdd(&acc[2], L);
        __threadfence();
        unsigned prev = atomicAdd((unsigned*)&acc[3], 1u);
        if (prev == fb::NBLK - 1) {
            float Pa = atomicAdd(&acc[0], 0.f);
            float Va = atomicAdd(&acc[1], 0.f);
            float La = atomicAdd(&acc[2], 0.f);
            float photo = Pa / (Va + 1e-6f);
            float lr = La / (Va + 1e-6f);
            out[0] = photo + 0.2f * lr;
            out[1] = photo;
            out[2] = lr;
            out[3] = Va * (1.f / (float)(Bn * Hn * Wn));
        }
    }
}

extern "C" void kernel_launch(void* const* d_in, const int* in_sizes, int n_in,
                              void* d_out, int out_size, void* d_ws, size_t ws_size,
                              hipStream_t stream) {
    const float* left   = (const float*)d_in[0];
    const float* right  = (const float*)d_in[1];
    const float* dl     = (const float*)d_in[2];
    const float* dr     = (const float*)d_in[3];
    const float* nonocc = (const float*)d_in[4];
    float* ws = (float*)d_ws;
    float* out = (float*)d_out;

    if (ws_size >= WS_NEED) {
        float* red1 = ws + RED1_OFF;
        float* red2 = ws + RED2_OFF;
        unsigned short* wbf = (unsigned short*)(ws + BF_OFF);
        float* vwp = ws + VW_OFF;
        pass_warp<<<NBLK1, TPB, 0, stream>>>(right, dl, dr, nonocc, wbf, vwp, red1);
        pass_ssim<<<NBLK2, TPB, 0, stream>>>(left, wbf, vwp, red2);
        pass_reduce<<<1, 1024, 0, stream>>>(red1, red2, out);
    } else {
        hipMemsetAsync(ws, 0, 4 * sizeof(float), stream);
        dim3 grid(fb::NBX, fb::NSTRIP, Bn);
        stereo_fallback<<<grid, TPB, 0, stream>>>(left, right, dl, dr, nonocc, ws, out);
    }
}